// Round 3
// baseline (61183.502 us; speedup 1.0000x reference)
//
#include <hip/hip_runtime.h>
#include <math.h>

// LSTM regressor: T=2048, B=256, I=256, H=512 (4H = 2048 gate rows).
// Round 3 resubmission: fp32 correctness-first baseline (rounds 0-2 never ran:
// GPU broker timeouts). Audited; unchanged from round 2.
//   - one fused kernel per timestep (input proj + recurrent proj + cell update)
//   - h stored as [H/4][B][4] -> per-lane float4 loads, coalesced 1KB/wave
//   - c stored transposed [k][b] for coalesced lane access
//   - wg owns 8 hidden indices x all 4 gates x 64 batches -> cell update local
//   - weight-row addresses wave-uniform (readfirstlane) -> scalar s_load path

#define T_STEPS 2048
#define BATCH   256
#define ISZ     256
#define HSZ     512

#define B_GRP 64      // batches per group (= wave width)
#define NGRP  4       // batch groups
#define KSL   8       // hidden indices per workgroup

__device__ __forceinline__ float sigm(float x) { return 1.0f / (1.0f + expf(-x)); }

// grid = 256 wgs (NGRP * 64 k-slices), block = 512 (8 waves)
__global__ __launch_bounds__(512)
void lstm_step_kernel(const float* __restrict__ x_t,    // [256][256] this step's input
                      const float* __restrict__ W_ih,   // [2048][256]
                      const float* __restrict__ W_hh,   // [2048][512]
                      const float* __restrict__ b_ih,   // [2048]
                      const float* __restrict__ b_hh,   // [2048]
                      const float* __restrict__ h_prev, // [128][256][4] packed
                      float* __restrict__ h_next,       // [128][256][4] packed
                      float* __restrict__ c_st)         // [512][256] transposed
{
    // row stride 260 dwords: lane-stride ≡ 4 mod 32 banks -> <=2-way aliasing
    // on ds_read_b128 (free per m136).
    __shared__ float x_lds[B_GRP][260];

    const int wg  = blockIdx.x;
    const int g   = wg >> 6;          // batch group 0..3
    const int w   = wg & 63;          // k-slice 0..63
    const int k0  = w * KSL;
    const int tid = threadIdx.x;

    // ---- stage this group's x slice [64 rows x 256 cols] into LDS ----
    {
        const int l  = tid & 63;      // col-quad
        const int rb = tid >> 6;      // 0..7
        #pragma unroll
        for (int s = 0; s < 8; ++s) {
            const int row = s * 8 + rb;            // 0..63
            const float4 v = *(const float4*)(x_t + (size_t)(g * B_GRP + row) * ISZ + l * 4);
            *(float4*)(&x_lds[row][l * 4]) = v;
        }
    }
    __syncthreads();

    const int b_l = tid & 63;                 // batch within group
    const int b   = g * B_GRP + b_l;          // global batch
    const int kl  = __builtin_amdgcn_readfirstlane(tid >> 6); // 0..7 wave-uniform
    const int k   = k0 + kl;                  // hidden index this thread owns

    // gate rows: q*512 + k  (PyTorch order i,f,g,o)
    float acc[4];
    #pragma unroll
    for (int q = 0; q < 4; ++q)
        acc[q] = b_ih[q * HSZ + k] + b_hh[q * HSZ + k];

    // ---- x part: K = 256 (x from LDS, weights wave-uniform -> s_load) ----
    #pragma unroll 4
    for (int j4 = 0; j4 < ISZ; j4 += 4) {
        const float4 xv = *(const float4*)(&x_lds[b_l][j4]);
        #pragma unroll
        for (int q = 0; q < 4; ++q) {
            const float4 wv = *(const float4*)(W_ih + (size_t)(q * HSZ + k) * ISZ + j4);
            acc[q] += xv.x * wv.x + xv.y * wv.y + xv.z * wv.z + xv.w * wv.w;
        }
    }

    // ---- h part: K = 512, h packed [j4][b][4] -> one b128 load per 4 j ----
    #pragma unroll 4
    for (int j4 = 0; j4 < HSZ; j4 += 4) {
        const float4 hv = *(const float4*)(h_prev + (size_t)(j4 >> 2) * (BATCH * 4) + b * 4);
        #pragma unroll
        for (int q = 0; q < 4; ++q) {
            const float4 wv = *(const float4*)(W_hh + (size_t)(q * HSZ + k) * HSZ + j4);
            acc[q] += hv.x * wv.x + hv.y * wv.y + hv.z * wv.z + hv.w * wv.w;
        }
    }

    // ---- cell update (fully local to this thread) ----
    const float ig = sigm(acc[0]);
    const float fg = sigm(acc[1]);
    const float gg = tanhf(acc[2]);
    const float og = sigm(acc[3]);

    const int cidx = k * BATCH + b;           // c: [k][b]
    const float c_new = fg * c_st[cidx] + ig * gg;
    c_st[cidx] = c_new;
    // h: packed [k/4][b][k&3]
    h_next[(size_t)(k >> 2) * (BATCH * 4) + b * 4 + (k & 3)] = og * tanhf(c_new);
}

// initialize packed h and transposed c from h0, c0 (row-major [b][k])
__global__ __launch_bounds__(256)
void lstm_init_kernel(const float* __restrict__ h0, const float* __restrict__ c0,
                      float* __restrict__ hP, float* __restrict__ cT)
{
    const int idx = blockIdx.x * 256 + threadIdx.x;   // 0 .. 131071
    const int b = idx >> 9;       // /512
    const int k = idx & 511;
    hP[(size_t)(k >> 2) * (BATCH * 4) + b * 4 + (k & 3)] = h0[idx];
    cT[k * BATCH + b] = c0[idx];
}

// out[b] = sum_k h_last[k][b] * W_dec[k] + b_dec
__global__ __launch_bounds__(256)
void lstm_decode_kernel(const float* __restrict__ hP, const float* __restrict__ W_dec,
                        const float* __restrict__ b_dec, float* __restrict__ out)
{
    const int b = threadIdx.x;    // 0..255
    float s = 0.0f;
    for (int j4 = 0; j4 < HSZ; j4 += 4) {
        const float4 hv = *(const float4*)(hP + (size_t)(j4 >> 2) * (BATCH * 4) + b * 4);
        s += hv.x * W_dec[j4 + 0] + hv.y * W_dec[j4 + 1]
           + hv.z * W_dec[j4 + 2] + hv.w * W_dec[j4 + 3];
    }
    out[b] = s + b_dec[0];
}

extern "C" void kernel_launch(void* const* d_in, const int* in_sizes, int n_in,
                              void* d_out, int out_size, void* d_ws, size_t ws_size,
                              hipStream_t stream) {
    const float* inputs = (const float*)d_in[0];   // [2048][256][256]
    const float* h0     = (const float*)d_in[1];   // [256][512]
    const float* c0     = (const float*)d_in[2];   // [256][512]
    const float* W_ih   = (const float*)d_in[3];   // [2048][256]
    const float* W_hh   = (const float*)d_in[4];   // [2048][512]
    const float* b_ih   = (const float*)d_in[5];   // [2048]
    const float* b_hh   = (const float*)d_in[6];   // [2048]
    const float* W_dec  = (const float*)d_in[7];   // [512]
    const float* b_dec  = (const float*)d_in[8];   // [1]
    float* out = (float*)d_out;                    // [256]

    float* ws  = (float*)d_ws;
    float* hP0 = ws;                    // [512*256] packed h buffer A
    float* hP1 = ws + 131072;           // [512*256] packed h buffer B
    float* cT  = ws + 262144;           // [512*256]

    hipLaunchKernelGGL(lstm_init_kernel, dim3(512), dim3(256), 0, stream,
                       h0, c0, hP0, cT);

    for (int t = 0; t < T_STEPS; ++t) {
        const float* x_t = inputs + (size_t)t * BATCH * ISZ;
        const float* hp  = (t & 1) ? hP1 : hP0;
        float*       hn  = (t & 1) ? hP0 : hP1;
        hipLaunchKernelGGL(lstm_step_kernel, dim3(NGRP * 64), dim3(512), 0, stream,
                           x_t, W_ih, W_hh, b_ih, b_hh, hp, hn, cT);
    }

    // T=2048 even -> final h is in hP0
    hipLaunchKernelGGL(lstm_decode_kernel, dim3(1), dim3(256), 0, stream,
                       hP0, W_dec, b_dec, out);
}

// Round 5
// 51846.191 us; speedup vs baseline: 1.1801x; 1.1801x over previous
//
#include <hip/hip_runtime.h>
#include <math.h>

// LSTM regressor: T=2048, B=256, I=256, H=512 (4H = 2048 gate rows).
// Round 5 resubmission of round-4 (broker timeout; never ran). Fixes
// round-3's measured 61 ms (30 us/step vs 5.1 us VALU floor).
//   theory: W streamed from L3 every step (per-XCD L2 thrash + scattered
//   block->XCD mapping) with only 2 waves/SIMD of latency hiding.
//   - K-split: block 1024 = 16 waves; jh=0 does x+h[0:128), jh=1 h[128:512);
//     LDS float4 reduce -> 4 waves/SIMD (2x hiding, half per-wave VMEM chain)
//   - XCD-aware bid remap: 4 batch-group wgs sharing a W slice -> same XCD
//     (per-XCD L2 working set ~2 MB < 4 MB -> W L2-resident)
//   - x LDS: XOR slot swizzle (j4 ^ (row&7)) -> conflict-free b128 reads
//   - h packed [H/4][B][4] -> per-lane float4 loads; c transposed [k][b]

#define T_STEPS 2048
#define BATCH   256
#define ISZ     256
#define HSZ     512

#define B_GRP 64      // batches per wg (= wave width)
#define KSL   8       // hidden indices per wg

__device__ __forceinline__ float sigm(float x) { return 1.0f / (1.0f + expf(-x)); }

// grid = 256 wgs (4 batch-groups x 64 k-slices), block = 1024 (16 waves)
__global__ __launch_bounds__(1024)
void lstm_step_kernel(const float* __restrict__ x_t,    // [256][256]
                      const float* __restrict__ W_ih,   // [2048][256]
                      const float* __restrict__ W_hh,   // [2048][512]
                      const float* __restrict__ b_ih,   // [2048]
                      const float* __restrict__ b_hh,   // [2048]
                      const float* __restrict__ h_prev, // [128][256][4] packed
                      float* __restrict__ h_next,       // [128][256][4] packed
                      float* __restrict__ c_st)         // [512][256] transposed
{
    __shared__ float4 x_lds[B_GRP * 64];   // [row][slot], slot = j4 ^ (row&7); 64 KB
    __shared__ float4 red[KSL * B_GRP];    // K-split partials; 8 KB

    // XCD-aware remap: XCD = bid%8 (round-robin); give each XCD 8 whole
    // k-slices x all 4 batch groups so a W slice is read by ONE XCD only.
    const int bid = blockIdx.x;
    const int rg  = (bid & 7) + ((bid >> 5) << 3);   // k-slice 0..63
    const int g   = (bid >> 3) & 3;                  // batch group 0..3
    const int k0  = rg * KSL;

    const int tid = threadIdx.x;
    const int b_l = tid & 63;                        // lane = batch-in-group
    const int wid = __builtin_amdgcn_readfirstlane(tid >> 6);  // wave 0..15
    const int kl  = wid & 7;                         // hidden index in slice
    const int jh  = wid >> 3;                        // K-half 0/1
    const int k   = k0 + kl;
    const int b   = g * B_GRP + b_l;

    // ---- stage x slice [64 rows x 256 cols] into LDS, XOR-swizzled ----
    #pragma unroll
    for (int s = 0; s < 4; ++s) {
        const int idx = tid + 1024 * s;              // 0..4095 float4 quads
        const int row = idx >> 6;
        const int l4  = idx & 63;
        const float4 v = *(const float4*)(x_t + ((size_t)(g * B_GRP + row) << 8) + (l4 << 2));
        x_lds[(row << 6) | (l4 ^ (row & 7))] = v;
    }
    __syncthreads();

    float acc0 = 0.f, acc1 = 0.f, acc2 = 0.f, acc3 = 0.f;

    if (jh == 0) {
        // x part: j 0..255 (from LDS; W_ih rows wave-uniform)
        #pragma unroll 2
        for (int j4 = 0; j4 < 64; ++j4) {
            const float4 xv = x_lds[(b_l << 6) | (j4 ^ (b_l & 7))];
            const float4 w0 = *(const float4*)(W_ih + (size_t)(0 * HSZ + k) * ISZ + (j4 << 2));
            const float4 w1 = *(const float4*)(W_ih + (size_t)(1 * HSZ + k) * ISZ + (j4 << 2));
            const float4 w2 = *(const float4*)(W_ih + (size_t)(2 * HSZ + k) * ISZ + (j4 << 2));
            const float4 w3 = *(const float4*)(W_ih + (size_t)(3 * HSZ + k) * ISZ + (j4 << 2));
            acc0 += xv.x * w0.x + xv.y * w0.y + xv.z * w0.z + xv.w * w0.w;
            acc1 += xv.x * w1.x + xv.y * w1.y + xv.z * w1.z + xv.w * w1.w;
            acc2 += xv.x * w2.x + xv.y * w2.y + xv.z * w2.z + xv.w * w2.w;
            acc3 += xv.x * w3.x + xv.y * w3.y + xv.z * w3.z + xv.w * w3.w;
        }
        // h part low: j 0..127
        #pragma unroll 2
        for (int j4 = 0; j4 < 32; ++j4) {
            const float4 hv = *(const float4*)(h_prev + ((size_t)j4 << 10) + (b << 2));
            const float4 w0 = *(const float4*)(W_hh + (size_t)(0 * HSZ + k) * HSZ + (j4 << 2));
            const float4 w1 = *(const float4*)(W_hh + (size_t)(1 * HSZ + k) * HSZ + (j4 << 2));
            const float4 w2 = *(const float4*)(W_hh + (size_t)(2 * HSZ + k) * HSZ + (j4 << 2));
            const float4 w3 = *(const float4*)(W_hh + (size_t)(3 * HSZ + k) * HSZ + (j4 << 2));
            acc0 += hv.x * w0.x + hv.y * w0.y + hv.z * w0.z + hv.w * w0.w;
            acc1 += hv.x * w1.x + hv.y * w1.y + hv.z * w1.z + hv.w * w1.w;
            acc2 += hv.x * w2.x + hv.y * w2.y + hv.z * w2.z + hv.w * w2.w;
            acc3 += hv.x * w3.x + hv.y * w3.y + hv.z * w3.z + hv.w * w3.w;
        }
    } else {
        // h part high: j 128..511
        #pragma unroll 2
        for (int j4 = 32; j4 < 128; ++j4) {
            const float4 hv = *(const float4*)(h_prev + ((size_t)j4 << 10) + (b << 2));
            const float4 w0 = *(const float4*)(W_hh + (size_t)(0 * HSZ + k) * HSZ + (j4 << 2));
            const float4 w1 = *(const float4*)(W_hh + (size_t)(1 * HSZ + k) * HSZ + (j4 << 2));
            const float4 w2 = *(const float4*)(W_hh + (size_t)(2 * HSZ + k) * HSZ + (j4 << 2));
            const float4 w3 = *(const float4*)(W_hh + (size_t)(3 * HSZ + k) * HSZ + (j4 << 2));
            acc0 += hv.x * w0.x + hv.y * w0.y + hv.z * w0.z + hv.w * w0.w;
            acc1 += hv.x * w1.x + hv.y * w1.y + hv.z * w1.z + hv.w * w1.w;
            acc2 += hv.x * w2.x + hv.y * w2.y + hv.z * w2.z + hv.w * w2.w;
            acc3 += hv.x * w3.x + hv.y * w3.y + hv.z * w3.z + hv.w * w3.w;
        }
        red[(kl << 6) | b_l] = make_float4(acc0, acc1, acc2, acc3);
    }
    __syncthreads();

    if (jh == 0) {
        const float4 r = red[(kl << 6) | b_l];
        acc0 += r.x + b_ih[0 * HSZ + k] + b_hh[0 * HSZ + k];
        acc1 += r.y + b_ih[1 * HSZ + k] + b_hh[1 * HSZ + k];
        acc2 += r.z + b_ih[2 * HSZ + k] + b_hh[2 * HSZ + k];
        acc3 += r.w + b_ih[3 * HSZ + k] + b_hh[3 * HSZ + k];

        const float ig = sigm(acc0);
        const float fg = sigm(acc1);
        const float gg = tanhf(acc2);
        const float og = sigm(acc3);

        const int cidx = k * BATCH + b;              // c: [k][b]
        const float c_new = fg * c_st[cidx] + ig * gg;
        c_st[cidx] = c_new;
        // h: packed [k/4][b][k&3]
        h_next[((size_t)(k >> 2) << 10) + (b << 2) + (k & 3)] = og * tanhf(c_new);
    }
}

// initialize packed h and transposed c from h0, c0 (row-major [b][k])
__global__ __launch_bounds__(256)
void lstm_init_kernel(const float* __restrict__ h0, const float* __restrict__ c0,
                      float* __restrict__ hP, float* __restrict__ cT)
{
    const int idx = blockIdx.x * 256 + threadIdx.x;   // 0 .. 131071
    const int b = idx >> 9;       // /512
    const int k = idx & 511;
    hP[((size_t)(k >> 2) << 10) + (b << 2) + (k & 3)] = h0[idx];
    cT[k * BATCH + b] = c0[idx];
}

// out[b] = sum_k h_last[k][b] * W_dec[k] + b_dec
__global__ __launch_bounds__(256)
void lstm_decode_kernel(const float* __restrict__ hP, const float* __restrict__ W_dec,
                        const float* __restrict__ b_dec, float* __restrict__ out)
{
    const int b = threadIdx.x;    // 0..255
    float s = 0.0f;
    for (int j4 = 0; j4 < HSZ; j4 += 4) {
        const float4 hv = *(const float4*)(hP + ((size_t)(j4 >> 2) << 10) + (b << 2));
        s += hv.x * W_dec[j4 + 0] + hv.y * W_dec[j4 + 1]
           + hv.z * W_dec[j4 + 2] + hv.w * W_dec[j4 + 3];
    }
    out[b] = s + b_dec[0];
}

extern "C" void kernel_launch(void* const* d_in, const int* in_sizes, int n_in,
                              void* d_out, int out_size, void* d_ws, size_t ws_size,
                              hipStream_t stream) {
    const float* inputs = (const float*)d_in[0];   // [2048][256][256]
    const float* h0     = (const float*)d_in[1];   // [256][512]
    const float* c0     = (const float*)d_in[2];   // [256][512]
    const float* W_ih   = (const float*)d_in[3];   // [2048][256]
    const float* W_hh   = (const float*)d_in[4];   // [2048][512]
    const float* b_ih   = (const float*)d_in[5];   // [2048]
    const float* b_hh   = (const float*)d_in[6];   // [2048]
    const float* W_dec  = (const float*)d_in[7];   // [512]
    const float* b_dec  = (const float*)d_in[8];   // [1]
    float* out = (float*)d_out;                    // [256]

    float* ws  = (float*)d_ws;
    float* hP0 = ws;                    // [512*256] packed h buffer A
    float* hP1 = ws + 131072;           // [512*256] packed h buffer B
    float* cT  = ws + 262144;           // [512*256]

    hipLaunchKernelGGL(lstm_init_kernel, dim3(512), dim3(256), 0, stream,
                       h0, c0, hP0, cT);

    for (int t = 0; t < T_STEPS; ++t) {
        const float* x_t = inputs + (size_t)t * BATCH * ISZ;
        const float* hp  = (t & 1) ? hP1 : hP0;
        float*       hn  = (t & 1) ? hP0 : hP1;
        hipLaunchKernelGGL(lstm_step_kernel, dim3(256), dim3(1024), 0, stream,
                           x_t, W_ih, W_hh, b_ih, b_hh, hp, hn, cT);
    }

    // T=2048 even -> final h is in hP0
    hipLaunchKernelGGL(lstm_decode_kernel, dim3(1), dim3(256), 0, stream,
                       hP0, W_dec, b_dec, out);
}